// Round 10
// baseline (363.331 us; speedup 1.0000x reference)
//
#include <hip/hip_runtime.h>

#define BB   2
#define CIN  8
#define COUT 16
#define HH   512
#define WW   1024
#define KK   9
#define NPIX (HH*WW)
#define COPY4 (1u << 20)   // uint4 elements per 16MB copy

typedef unsigned int u32;
typedef float f32x4 __attribute__((ext_vector_type(4)));
typedef float f32x2 __attribute__((ext_vector_type(2)));

#define SB() __builtin_amdgcn_sched_barrier(0)

// fp32 -> bf16 bits, round-nearest-even
__device__ __forceinline__ u32 f2bf(float f) {
  u32 u = __float_as_uint(f);
  return (u + 0x7fffu + ((u >> 16) & 1u)) >> 16;
}
__device__ __forceinline__ float bflo(u32 u) { return __uint_as_float(u << 16); }
__device__ __forceinline__ float bfhi(u32 u) { return __uint_as_float(u & 0xffff0000u); }
__device__ __forceinline__ u32 comp4(uint4 v, int j) {
  return j == 0 ? v.x : j == 1 ? v.y : j == 2 ? v.z : v.w;
}

// ============ 4-copy 2D-parity layout ============
// copy (pyp,pxp): 2x2-pixel blocks starting at rows 2*by+pyp, cols 2*bx+pxp.
// uint4 index = (pyp*2+pxp)<<20 + ((by*512+bx)*2 + b)*4 + dy*2 + dx
// (by,bx) pair-block = 128B contiguous: b0's 64B block then b1's 64B block.

// One thread per (by,bx,b): reads its 3x3 fp32 neighborhood for ONE batch,
// writes complete 64B blocks; thread pairs (b=t&1) make 128B-contiguous stores.
__global__ __launch_bounds__(256) void xpose3c_k(const float* __restrict__ x,
                                                 uint4* __restrict__ xt4) {
  int t = blockIdx.x * 256 + threadIdx.x;
  if (t >= (HH / 2) * (WW / 2) * BB) return;
  int b  = t & 1;
  int s  = t >> 1;
  int by = s >> 9;          // 512 block-cols
  int bx = s & 511;

  u32 pk[3][3][4];          // [r][colOff][chpair]
  #pragma unroll
  for (int j = 0; j < 4; ++j) {
    const float* c0 = x + (size_t)(b * CIN + 2 * j    ) * NPIX;
    const float* c1 = x + (size_t)(b * CIN + 2 * j + 1) * NPIX;
    int i1 = min(bx + 1, WW / 2 - 1);
    #pragma unroll
    for (int r = 0; r < 3; ++r) {
      int row = min(2 * by + r, HH - 1);
      const float2* p0 = (const float2*)(c0 + (size_t)row * WW);
      const float2* p1 = (const float2*)(c1 + (size_t)row * WW);
      float2 a0 = p0[bx], a1 = p0[i1];
      float2 b0 = p1[bx], b1 = p1[i1];
      pk[r][0][j] = f2bf(a0.x) | (f2bf(b0.x) << 16);
      pk[r][1][j] = f2bf(a0.y) | (f2bf(b0.y) << 16);
      pk[r][2][j] = f2bf(a1.x) | (f2bf(b1.x) << 16);
    }
  }

  #pragma unroll
  for (int pyp = 0; pyp < 2; ++pyp)
    #pragma unroll
    for (int pxp = 0; pxp < 2; ++pxp) {
      u32 base = ((u32)(pyp * 2 + pxp) << 20)
               + ((u32)(by * 512 + bx) * 2 + (u32)b) * 4;
      #pragma unroll
      for (int d = 0; d < 4; ++d) {
        int dy = d >> 1, dx = d & 1;
        uint4 v;
        v.x = pk[pyp + dy][pxp + dx][0];
        v.y = pk[pyp + dy][pxp + dx][1];
        v.z = pk[pyp + dy][pxp + dx][2];
        v.w = pk[pyp + dy][pxp + dx][3];
        xt4[base + d] = v;
      }
    }
}

// One thread = one PIXEL (both batches): each sample is one 128B contiguous
// span (8 x dwordx4). Honest depth-2 ping-pong, R8-proven SB structure.
__global__ __launch_bounds__(256, 4) void mconv8_k(const uint4* __restrict__ xt4,
                                                   const float* __restrict__ sm,
                                                   const float* __restrict__ weight,
                                                   const float* __restrict__ bias,
                                                   float* __restrict__ out) {
  __shared__ float sml[256 * KK * 2];              // 18.4 KB
  __shared__ float wlds[KK * CIN * COUT];          // [k][c][o], 4.6 KB

  int tid = threadIdx.x;
  {
    const f32x4* g = (const f32x4*)(sm + (size_t)blockIdx.x * 256 * KK * 2);
    f32x4* l = (f32x4*)sml;
    for (int i = tid; i < 256 * KK * 2 / 4; i += 256)
      l[i] = __builtin_nontemporal_load(g + i);
  }
  for (int i = tid; i < KK * CIN * COUT; i += 256) {
    int k = i >> 7, c = (i >> 4) & 7, o = i & 15;
    wlds[i] = weight[(o * CIN + c) * KK + k];
  }
  __syncthreads();

  const int p = blockIdx.x * 256 + tid;

  f32x2 acc2[16];                      // [b*8 + o2]
  #pragma unroll
  for (int o2 = 0; o2 < 8; ++o2) {
    f32x2 bv; bv[0] = bias[2*o2]; bv[1] = bias[2*o2+1];
    acc2[o2] = bv; acc2[8 + o2] = bv;
  }

  const float2* smp = (const float2*)sml + tid * KK;

  // precompute the 9 pair-block indices (uint4 units; 128B per sample)
  u32 iq[9];
  #pragma unroll
  for (int k = 0; k < KK; ++k) {
    float2 s = smp[k];
    int x0 = min(max((int)floorf(s.x), 0), WW - 2);
    int y0 = min(max((int)floorf(s.y), 0), HH - 2);
    iq[k] = ((u32)((y0 & 1) * 2 + (x0 & 1)) << 20)
          + ((u32)((y0 >> 1) * 512 + (x0 >> 1)) * 8);
  }

  auto LOADK = [&](int k, uint4 (&v)[8]) {
    const uint4* a = xt4 + iq[k];
    #pragma unroll
    for (int j = 0; j < 8; ++j) v[j] = a[j];
  };

  auto CONS = [&](int k, uint4 (&v)[8]) {
    float2 s = smp[k];
    float x0f = floorf(s.x), y0f = floorf(s.y);
    float wx = s.x - x0f, wy = s.y - y0f;
    float w00 = (1.f - wy) * (1.f - wx), w01 = (1.f - wy) * wx;
    float w10 = wy * (1.f - wx),         w11 = wy * wx;
    const float4* w4 = (const float4*)&wlds[k * (CIN * COUT)];

    #pragma unroll
    for (int b = 0; b < 2; ++b) {
      float sv[8];
      #pragma unroll
      for (int j = 0; j < 4; ++j) {
        u32 a00 = comp4(v[4*b+0], j), a01 = comp4(v[4*b+1], j);
        u32 a10 = comp4(v[4*b+2], j), a11 = comp4(v[4*b+3], j);
        sv[2*j]   = w00*bflo(a00) + w01*bflo(a01) + w10*bflo(a10) + w11*bflo(a11);
        sv[2*j+1] = w00*bfhi(a00) + w01*bfhi(a01) + w10*bfhi(a10) + w11*bfhi(a11);
      }
      #pragma unroll
      for (int c = 0; c < 8; ++c) {
        float s0 = sv[c];
        #pragma unroll
        for (int og = 0; og < 4; ++og) {
          float4 wv = w4[c * 4 + og];
          f32x2 wlo; wlo[0] = wv.x; wlo[1] = wv.y;
          f32x2 whi; whi[0] = wv.z; whi[1] = wv.w;
          acc2[b*8 + og*2]     += wlo * s0;   // v_pk_fma_f32
          acc2[b*8 + og*2 + 1] += whi * s0;
        }
      }
    }
  };

  uint4 va[8], vb[8];
  LOADK(0, va); SB(); LOADK(1, vb); SB();
  CONS(0, va);  SB(); LOADK(2, va); SB();
  CONS(1, vb);  SB(); LOADK(3, vb); SB();
  CONS(2, va);  SB(); LOADK(4, va); SB();
  CONS(3, vb);  SB(); LOADK(5, vb); SB();
  CONS(4, va);  SB(); LOADK(6, va); SB();
  CONS(5, vb);  SB(); LOADK(7, vb); SB();
  CONS(6, va);  SB(); LOADK(8, va); SB();
  CONS(7, vb);  SB();
  CONS(8, va);

  #pragma unroll
  for (int b = 0; b < 2; ++b)
    #pragma unroll
    for (int o2 = 0; o2 < 8; ++o2) {
      __builtin_nontemporal_store(acc2[b*8+o2][0], &out[(size_t)(b * COUT + 2*o2    ) * NPIX + p]);
      __builtin_nontemporal_store(acc2[b*8+o2][1], &out[(size_t)(b * COUT + 2*o2 + 1) * NPIX + p]);
    }
}

// fallback if workspace too small: gather directly from fp32 x [B][C][H][W]
__global__ __launch_bounds__(256) void mconv_direct_k(const float* __restrict__ x,
                                                      const float* __restrict__ sm,
                                                      const float* __restrict__ weight,
                                                      const float* __restrict__ bias,
                                                      float* __restrict__ out) {
  __shared__ float wlds[KK * CIN * COUT];
  int tid = threadIdx.x;
  for (int i = tid; i < KK * CIN * COUT; i += 256) {
    int k = i >> 7, c = (i >> 4) & 7, o = i & 15;
    wlds[i] = weight[(o * CIN + c) * KK + k];
  }
  __syncthreads();

  int p = blockIdx.x * 256 + tid;
  if (p >= NPIX) return;

  float acc[2][COUT];
  #pragma unroll
  for (int o = 0; o < COUT; ++o) { float bv = bias[o]; acc[0][o] = bv; acc[1][o] = bv; }

  const float2* smp = (const float2*)sm;

  for (int k = 0; k < KK; ++k) {
    float2 s = smp[(size_t)p * KK + k];
    float x0f = floorf(s.x), y0f = floorf(s.y);
    float wx = s.x - x0f, wy = s.y - y0f;
    int x0 = min(max((int)x0f, 0), WW - 1);
    int y0 = min(max((int)y0f, 0), HH - 1);
    int x1 = min(x0 + 1, WW - 1), y1 = min(y0 + 1, HH - 1);
    float w00 = (1.f - wy) * (1.f - wx), w01 = (1.f - wy) * wx;
    float w10 = wy * (1.f - wx),         w11 = wy * wx;

    float sv[2][8];
    #pragma unroll
    for (int b = 0; b < 2; ++b) {
      #pragma unroll
      for (int c = 0; c < 8; ++c) {
        const float* xp = x + (size_t)(b * CIN + c) * NPIX;
        float v00 = xp[y0 * WW + x0], v01 = xp[y0 * WW + x1];
        float v10 = xp[y1 * WW + x0], v11 = xp[y1 * WW + x1];
        sv[b][c] = w00 * v00 + w01 * v01 + w10 * v10 + w11 * v11;
      }
    }

    const float4* w4 = (const float4*)&wlds[k * (CIN * COUT)];
    #pragma unroll
    for (int c = 0; c < 8; ++c) {
      float s0 = sv[0][c], s1 = sv[1][c];
      #pragma unroll
      for (int og = 0; og < 4; ++og) {
        float4 wv = w4[c * 4 + og];
        acc[0][og*4+0] += s0 * wv.x; acc[1][og*4+0] += s1 * wv.x;
        acc[0][og*4+1] += s0 * wv.y; acc[1][og*4+1] += s1 * wv.y;
        acc[0][og*4+2] += s0 * wv.z; acc[1][og*4+2] += s1 * wv.z;
        acc[0][og*4+3] += s0 * wv.w; acc[1][og*4+3] += s1 * wv.w;
      }
    }
  }

  #pragma unroll
  for (int b = 0; b < 2; ++b)
    #pragma unroll
    for (int o = 0; o < COUT; ++o)
      out[(size_t)(b * COUT + o) * NPIX + p] = acc[b][o];
}

extern "C" void kernel_launch(void* const* d_in, const int* in_sizes, int n_in,
                              void* d_out, int out_size, void* d_ws, size_t ws_size,
                              hipStream_t stream) {
  const float* x      = (const float*)d_in[0];
  const float* sm     = (const float*)d_in[1];
  const float* weight = (const float*)d_in[2];
  const float* bias   = (const float*)d_in[3];
  float* out = (float*)d_out;

  const size_t oneCopy = (size_t)COPY4 * sizeof(uint4);   // 16 MB
  uint4* xt4 = (uint4*)d_ws;
  if (ws_size >= 4 * oneCopy) {
    hipLaunchKernelGGL(xpose3c_k, dim3((HH / 2) * (WW / 2) * BB / 256), dim3(256), 0,
                       stream, x, xt4);
    hipLaunchKernelGGL(mconv8_k, dim3(NPIX / 256), dim3(256), 0, stream,
                       xt4, sm, weight, bias, out);
  } else {
    hipLaunchKernelGGL(mconv_direct_k, dim3((NPIX + 255) / 256), dim3(256), 0, stream,
                       x, sm, weight, bias, out);
  }
}

// Round 11
// 139.054 us; speedup vs baseline: 2.6129x; 2.6129x over previous
//
#include <hip/hip_runtime.h>

#define BB   2
#define CIN  8
#define COUT 16
#define HH   512
#define WW   1024
#define KK   9
#define NPIX (HH*WW)
#define COPY4 (1u << 20)   // uint4 elements per 16MB copy

typedef unsigned int u32;
typedef float f32x4 __attribute__((ext_vector_type(4)));
typedef float f32x2 __attribute__((ext_vector_type(2)));

#define SB() __builtin_amdgcn_sched_barrier(0)

// fp32 -> bf16 bits, round-nearest-even
__device__ __forceinline__ u32 f2bf(float f) {
  u32 u = __float_as_uint(f);
  return (u + 0x7fffu + ((u >> 16) & 1u)) >> 16;
}
__device__ __forceinline__ float bflo(u32 u) { return __uint_as_float(u << 16); }
__device__ __forceinline__ float bfhi(u32 u) { return __uint_as_float(u & 0xffff0000u); }
__device__ __forceinline__ u32 comp4(uint4 v, int j) {
  return j == 0 ? v.x : j == 1 ? v.y : j == 2 ? v.z : v.w;
}

// ============ 4-copy 2D-parity layout ============
// copy (pyp,pxp): 2x2-pixel blocks starting at rows 2*by+pyp, cols 2*bx+pxp.
// uint4 index = (pyp*2+pxp)<<20 + ((by*512+bx)*2 + b)*4 + dy*2 + dx
// (by,bx) pair-block = 128B contiguous: b0's 64B block then b1's 64B block.

// One thread per (by,bx,b): reads its 3x3 fp32 neighborhood for ONE batch,
// writes complete 64B blocks; thread pairs (b=t&1) make 128B-contiguous stores.
__global__ __launch_bounds__(256) void xpose3c_k(const float* __restrict__ x,
                                                 uint4* __restrict__ xt4) {
  int t = blockIdx.x * 256 + threadIdx.x;
  if (t >= (HH / 2) * (WW / 2) * BB) return;
  int b  = t & 1;
  int s  = t >> 1;
  int by = s >> 9;          // 512 block-cols
  int bx = s & 511;

  u32 pk[3][3][4];          // [r][colOff][chpair]
  #pragma unroll
  for (int j = 0; j < 4; ++j) {
    const float* c0 = x + (size_t)(b * CIN + 2 * j    ) * NPIX;
    const float* c1 = x + (size_t)(b * CIN + 2 * j + 1) * NPIX;
    int i1 = min(bx + 1, WW / 2 - 1);
    #pragma unroll
    for (int r = 0; r < 3; ++r) {
      int row = min(2 * by + r, HH - 1);
      const float2* p0 = (const float2*)(c0 + (size_t)row * WW);
      const float2* p1 = (const float2*)(c1 + (size_t)row * WW);
      float2 a0 = p0[bx], a1 = p0[i1];
      float2 b0 = p1[bx], b1 = p1[i1];
      pk[r][0][j] = f2bf(a0.x) | (f2bf(b0.x) << 16);
      pk[r][1][j] = f2bf(a0.y) | (f2bf(b0.y) << 16);
      pk[r][2][j] = f2bf(a1.x) | (f2bf(b1.x) << 16);
    }
  }

  #pragma unroll
  for (int pyp = 0; pyp < 2; ++pyp)
    #pragma unroll
    for (int pxp = 0; pxp < 2; ++pxp) {
      u32 base = ((u32)(pyp * 2 + pxp) << 20)
               + ((u32)(by * 512 + bx) * 2 + (u32)b) * 4;
      #pragma unroll
      for (int d = 0; d < 4; ++d) {
        int dy = d >> 1, dx = d & 1;
        uint4 v;
        v.x = pk[pyp + dy][pxp + dx][0];
        v.y = pk[pyp + dy][pxp + dx][1];
        v.z = pk[pyp + dy][pxp + dx][2];
        v.w = pk[pyp + dy][pxp + dx][3];
        xt4[base + d] = v;
      }
    }
}

// One thread = one (pixel,batch), R8-proven depth-4 structure. KEY CHANGE vs R8:
// b = tid&1 (lane-paired batches) so lanes 2i,2i+1 request the two adjacent
// 64B halves of ONE 128B pair-block in the same instruction -> 32 x 128B line
// requests per wave instead of 64 scattered 64B requests.
__global__ __launch_bounds__(256) void mconv9_k(const uint4* __restrict__ xt4,
                                                const float* __restrict__ sm,
                                                const float* __restrict__ weight,
                                                const float* __restrict__ bias,
                                                float* __restrict__ out) {
  __shared__ float sml[128 * KK * 2];
  __shared__ float wlds[KK * CIN * COUT];          // [k][c][o]

  int tid = threadIdx.x;
  {
    const f32x4* g = (const f32x4*)(sm + (size_t)blockIdx.x * 128 * KK * 2);
    f32x4* l = (f32x4*)sml;
    for (int i = tid; i < 128 * KK * 2 / 4; i += 256) l[i] = g[i];
  }
  for (int i = tid; i < KK * CIN * COUT; i += 256) {
    int k = i >> 7, c = (i >> 4) & 7, o = i & 15;
    wlds[i] = weight[(o * CIN + c) * KK + k];
  }
  __syncthreads();

  const int b  = tid & 1;          // batch  (lane-paired!)
  const int pl = tid >> 1;         // pixel within block
  const int p  = blockIdx.x * 128 + pl;

  f32x2 acc2[8];
  #pragma unroll
  for (int o2 = 0; o2 < 8; ++o2) { acc2[o2][0] = bias[2*o2]; acc2[o2][1] = bias[2*o2+1]; }

  const float2* smp = (const float2*)sml + pl * KK;

  auto LOADK = [&](int k, uint4 (&v)[4]) {
    float2 s = smp[k];
    int x0 = min(max((int)floorf(s.x), 0), WW - 2);
    int y0 = min(max((int)floorf(s.y), 0), HH - 2);
    u32 idx = ((u32)((y0 & 1) * 2 + (x0 & 1)) << 20)
            + ((u32)((y0 >> 1) * 512 + (x0 >> 1)) * 2 + (u32)b) * 4;
    v[0] = xt4[idx];     v[1] = xt4[idx + 1];
    v[2] = xt4[idx + 2]; v[3] = xt4[idx + 3];
  };

  auto CONS = [&](int k, uint4 (&v)[4]) {
    float2 s = smp[k];
    float x0f = floorf(s.x), y0f = floorf(s.y);
    float wx = s.x - x0f, wy = s.y - y0f;
    float w00 = (1.f - wy) * (1.f - wx), w01 = (1.f - wy) * wx;
    float w10 = wy * (1.f - wx),         w11 = wy * wx;
    const float4* w4 = (const float4*)&wlds[k * (CIN * COUT)];

    float sv[8];
    #pragma unroll
    for (int j = 0; j < 4; ++j) {
      u32 a00 = comp4(v[0], j), a01 = comp4(v[1], j);
      u32 a10 = comp4(v[2], j), a11 = comp4(v[3], j);
      sv[2*j]   = w00*bflo(a00) + w01*bflo(a01) + w10*bflo(a10) + w11*bflo(a11);
      sv[2*j+1] = w00*bfhi(a00) + w01*bfhi(a01) + w10*bfhi(a10) + w11*bfhi(a11);
    }
    #pragma unroll
    for (int c = 0; c < 8; ++c) {
      float s0 = sv[c];
      #pragma unroll
      for (int og = 0; og < 4; ++og) {
        float4 wv = w4[c * 4 + og];
        f32x2 wlo; wlo[0] = wv.x; wlo[1] = wv.y;
        f32x2 whi; whi[0] = wv.z; whi[1] = wv.w;
        acc2[og*2]   += wlo * s0;     // v_pk_fma_f32
        acc2[og*2+1] += whi * s0;
      }
    }
  };

  uint4 va[4], vb[4], vc[4], vd[4];
  LOADK(0, va); LOADK(1, vb); LOADK(2, vc); LOADK(3, vd); SB();
  CONS(0, va);  SB(); LOADK(4, va); SB();
  CONS(1, vb);  SB(); LOADK(5, vb); SB();
  CONS(2, vc);  SB(); LOADK(6, vc); SB();
  CONS(3, vd);  SB(); LOADK(7, vd); SB();
  CONS(4, va);  SB(); LOADK(8, va); SB();
  CONS(5, vb);  SB();
  CONS(6, vc);  SB();
  CONS(7, vd);  SB();
  CONS(8, va);

  #pragma unroll
  for (int o2 = 0; o2 < 8; ++o2) {
    __builtin_nontemporal_store(acc2[o2][0], &out[(size_t)(b * COUT + 2*o2    ) * NPIX + p]);
    __builtin_nontemporal_store(acc2[o2][1], &out[(size_t)(b * COUT + 2*o2 + 1) * NPIX + p]);
  }
}

// fallback if workspace too small: gather directly from fp32 x [B][C][H][W]
__global__ __launch_bounds__(256) void mconv_direct_k(const float* __restrict__ x,
                                                      const float* __restrict__ sm,
                                                      const float* __restrict__ weight,
                                                      const float* __restrict__ bias,
                                                      float* __restrict__ out) {
  __shared__ float wlds[KK * CIN * COUT];
  int tid = threadIdx.x;
  for (int i = tid; i < KK * CIN * COUT; i += 256) {
    int k = i >> 7, c = (i >> 4) & 7, o = i & 15;
    wlds[i] = weight[(o * CIN + c) * KK + k];
  }
  __syncthreads();

  int p = blockIdx.x * 256 + tid;
  if (p >= NPIX) return;

  float acc[2][COUT];
  #pragma unroll
  for (int o = 0; o < COUT; ++o) { float bv = bias[o]; acc[0][o] = bv; acc[1][o] = bv; }

  const float2* smp = (const float2*)sm;

  for (int k = 0; k < KK; ++k) {
    float2 s = smp[(size_t)p * KK + k];
    float x0f = floorf(s.x), y0f = floorf(s.y);
    float wx = s.x - x0f, wy = s.y - y0f;
    int x0 = min(max((int)x0f, 0), WW - 1);
    int y0 = min(max((int)y0f, 0), HH - 1);
    int x1 = min(x0 + 1, WW - 1), y1 = min(y0 + 1, HH - 1);
    float w00 = (1.f - wy) * (1.f - wx), w01 = (1.f - wy) * wx;
    float w10 = wy * (1.f - wx),         w11 = wy * wx;

    float sv[2][8];
    #pragma unroll
    for (int b = 0; b < 2; ++b) {
      #pragma unroll
      for (int c = 0; c < 8; ++c) {
        const float* xp = x + (size_t)(b * CIN + c) * NPIX;
        float v00 = xp[y0 * WW + x0], v01 = xp[y0 * WW + x1];
        float v10 = xp[y1 * WW + x0], v11 = xp[y1 * WW + x1];
        sv[b][c] = w00 * v00 + w01 * v01 + w10 * v10 + w11 * v11;
      }
    }

    const float4* w4 = (const float4*)&wlds[k * (CIN * COUT)];
    #pragma unroll
    for (int c = 0; c < 8; ++c) {
      float s0 = sv[0][c], s1 = sv[1][c];
      #pragma unroll
      for (int og = 0; og < 4; ++og) {
        float4 wv = w4[c * 4 + og];
        acc[0][og*4+0] += s0 * wv.x; acc[1][og*4+0] += s1 * wv.x;
        acc[0][og*4+1] += s0 * wv.y; acc[1][og*4+1] += s1 * wv.y;
        acc[0][og*4+2] += s0 * wv.z; acc[1][og*4+2] += s1 * wv.z;
        acc[0][og*4+3] += s0 * wv.w; acc[1][og*4+3] += s1 * wv.w;
      }
    }
  }

  #pragma unroll
  for (int b = 0; b < 2; ++b)
    #pragma unroll
    for (int o = 0; o < COUT; ++o)
      out[(size_t)(b * COUT + o) * NPIX + p] = acc[b][o];
}

extern "C" void kernel_launch(void* const* d_in, const int* in_sizes, int n_in,
                              void* d_out, int out_size, void* d_ws, size_t ws_size,
                              hipStream_t stream) {
  const float* x      = (const float*)d_in[0];
  const float* sm     = (const float*)d_in[1];
  const float* weight = (const float*)d_in[2];
  const float* bias   = (const float*)d_in[3];
  float* out = (float*)d_out;

  const size_t oneCopy = (size_t)COPY4 * sizeof(uint4);   // 16 MB
  uint4* xt4 = (uint4*)d_ws;
  if (ws_size >= 4 * oneCopy) {
    hipLaunchKernelGGL(xpose3c_k, dim3((HH / 2) * (WW / 2) * BB / 256), dim3(256), 0,
                       stream, x, xt4);
    hipLaunchKernelGGL(mconv9_k, dim3(NPIX / 128), dim3(256), 0, stream,
                       xt4, sm, weight, bias, out);
  } else {
    hipLaunchKernelGGL(mconv_direct_k, dim3((NPIX + 255) / 256), dim3(256), 0, stream,
                       x, sm, weight, bias, out);
  }
}

// Round 12
// 126.227 us; speedup vs baseline: 2.8784x; 1.1016x over previous
//
#include <hip/hip_runtime.h>

#define BB   2
#define CIN  8
#define COUT 16
#define HH   512
#define WW   1024
#define KK   9
#define NPIX (HH*WW)
#define COPY4 (1u << 20)   // uint4 elements per 16MB copy

typedef unsigned int u32;
typedef float f32x4 __attribute__((ext_vector_type(4)));
typedef float f32x2 __attribute__((ext_vector_type(2)));

#define SB() __builtin_amdgcn_sched_barrier(0)

// fp32 -> bf16 bits, round-nearest-even
__device__ __forceinline__ u32 f2bf(float f) {
  u32 u = __float_as_uint(f);
  return (u + 0x7fffu + ((u >> 16) & 1u)) >> 16;
}
__device__ __forceinline__ float bflo(u32 u) { return __uint_as_float(u << 16); }
__device__ __forceinline__ float bfhi(u32 u) { return __uint_as_float(u & 0xffff0000u); }
__device__ __forceinline__ u32 comp4(uint4 v, int j) {
  return j == 0 ? v.x : j == 1 ? v.y : j == 2 ? v.z : v.w;
}

// ============ 4-copy 2D-parity layout ============
// copy (pyp,pxp): 2x2-pixel blocks at origins (2by+pyp, 2bx+pxp).
// uint4 index = (pyp*2+pxp)<<20 + ((by*512+bx)*2 + b)*4 + dy*2 + dx
// One 64B block = 2y x 2x x 8ch bf16 of one batch; batches adjacent (128B pair).

// LDS-staged transpose: one workgroup = one 32x32-pixel tile (+1 halo).
// Phase 1: stage 33x33 x 2 batches packed-bf16 uint4 in LDS (coalesced reads).
// Phase 2: write 2048 complete 64B blocks, waves store 1KB-contiguous runs.
__global__ __launch_bounds__(256) void xpose4_k(const float* __restrict__ x,
                                                uint4* __restrict__ xt4) {
  __shared__ uint4 lds_px[33 * 2 * 33];            // [(py*2+b)*33 + px], 34.8 KB

  const int tile = blockIdx.x;                     // 16 x 32 tiles
  const int ty = tile >> 5;                        // tile row   (32 cols of tiles)
  const int tx = tile & 31;                        // tile col
  const int tid = threadIdx.x;

  // ---- stage 33*33*2 = 2178 entries ----
  for (int e = tid; e < 33 * 33 * 2; e += 256) {
    int py  = e / 66;
    int rem = e - py * 66;
    int b   = rem >= 33;
    int px  = rem - (b ? 33 : 0);
    int gy = min(ty * 32 + py, HH - 1);
    int gx = min(tx * 32 + px, WW - 1);
    const float* base = x + (size_t)gy * WW + gx;
    u32 pk[4];
    #pragma unroll
    for (int j = 0; j < 4; ++j) {
      float f0 = base[(size_t)(b * CIN + 2 * j    ) * NPIX];
      float f1 = base[(size_t)(b * CIN + 2 * j + 1) * NPIX];
      pk[j] = f2bf(f0) | (f2bf(f1) << 16);
    }
    uint4 v; v.x = pk[0]; v.y = pk[1]; v.z = pk[2]; v.w = pk[3];
    lds_px[e] = v;
  }
  __syncthreads();

  // ---- write 2048 blocks = 8192 uint4, 1KB-contiguous per wave-instr ----
  #pragma unroll
  for (int it = 0; it < 32; ++it) {
    int w   = it * 256 + tid;
    int d   = w & 3;
    int b   = (w >> 2) & 1;
    int bxl = (w >> 3) & 15;
    int oyp = (w >> 7) & 15;
    int c   = (w >> 11) & 3;
    int pyp = c >> 1, pxp = c & 1;
    int row = 2 * oyp + pyp + (d >> 1);
    int col = 2 * bxl + pxp + (d & 1);
    uint4 v = lds_px[(row * 2 + b) * 33 + col];
    u32 by_g = (u32)(ty * 16 + oyp);
    u32 bx_g = (u32)(tx * 16 + bxl);
    u32 addr = ((u32)c << 20) + ((by_g * 512 + bx_g) * 2 + (u32)b) * 4 + (u32)d;
    xt4[addr] = v;
  }
}

// One thread = one (pixel,batch), b = tid&1 so lane pairs fetch the two
// adjacent 64B halves of one 128B pair-block in the same instruction.
// Depth-4 ping-pong, pk_fma epilogue. (R11: at the ~40 outstanding-miss/CU wall.)
__global__ __launch_bounds__(256) void mconv9_k(const uint4* __restrict__ xt4,
                                                const float* __restrict__ sm,
                                                const float* __restrict__ weight,
                                                const float* __restrict__ bias,
                                                float* __restrict__ out) {
  __shared__ float sml[128 * KK * 2];
  __shared__ float wlds[KK * CIN * COUT];          // [k][c][o]

  int tid = threadIdx.x;
  {
    const f32x4* g = (const f32x4*)(sm + (size_t)blockIdx.x * 128 * KK * 2);
    f32x4* l = (f32x4*)sml;
    for (int i = tid; i < 128 * KK * 2 / 4; i += 256) l[i] = g[i];
  }
  for (int i = tid; i < KK * CIN * COUT; i += 256) {
    int k = i >> 7, c = (i >> 4) & 7, o = i & 15;
    wlds[i] = weight[(o * CIN + c) * KK + k];
  }
  __syncthreads();

  const int b  = tid & 1;          // batch  (lane-paired!)
  const int pl = tid >> 1;         // pixel within block
  const int p  = blockIdx.x * 128 + pl;

  f32x2 acc2[8];
  #pragma unroll
  for (int o2 = 0; o2 < 8; ++o2) { acc2[o2][0] = bias[2*o2]; acc2[o2][1] = bias[2*o2+1]; }

  const float2* smp = (const float2*)sml + pl * KK;

  auto LOADK = [&](int k, uint4 (&v)[4]) {
    float2 s = smp[k];
    int x0 = min(max((int)floorf(s.x), 0), WW - 2);
    int y0 = min(max((int)floorf(s.y), 0), HH - 2);
    u32 idx = ((u32)((y0 & 1) * 2 + (x0 & 1)) << 20)
            + ((u32)((y0 >> 1) * 512 + (x0 >> 1)) * 2 + (u32)b) * 4;
    v[0] = xt4[idx];     v[1] = xt4[idx + 1];
    v[2] = xt4[idx + 2]; v[3] = xt4[idx + 3];
  };

  auto CONS = [&](int k, uint4 (&v)[4]) {
    float2 s = smp[k];
    float x0f = floorf(s.x), y0f = floorf(s.y);
    float wx = s.x - x0f, wy = s.y - y0f;
    float w00 = (1.f - wy) * (1.f - wx), w01 = (1.f - wy) * wx;
    float w10 = wy * (1.f - wx),         w11 = wy * wx;
    const float4* w4 = (const float4*)&wlds[k * (CIN * COUT)];

    float sv[8];
    #pragma unroll
    for (int j = 0; j < 4; ++j) {
      u32 a00 = comp4(v[0], j), a01 = comp4(v[1], j);
      u32 a10 = comp4(v[2], j), a11 = comp4(v[3], j);
      sv[2*j]   = w00*bflo(a00) + w01*bflo(a01) + w10*bflo(a10) + w11*bflo(a11);
      sv[2*j+1] = w00*bfhi(a00) + w01*bfhi(a01) + w10*bfhi(a10) + w11*bfhi(a11);
    }
    #pragma unroll
    for (int c = 0; c < 8; ++c) {
      float s0 = sv[c];
      #pragma unroll
      for (int og = 0; og < 4; ++og) {
        float4 wv = w4[c * 4 + og];
        f32x2 wlo; wlo[0] = wv.x; wlo[1] = wv.y;
        f32x2 whi; whi[0] = wv.z; whi[1] = wv.w;
        acc2[og*2]   += wlo * s0;     // v_pk_fma_f32
        acc2[og*2+1] += whi * s0;
      }
    }
  };

  uint4 va[4], vb[4], vc[4], vd[4];
  LOADK(0, va); LOADK(1, vb); LOADK(2, vc); LOADK(3, vd); SB();
  CONS(0, va);  SB(); LOADK(4, va); SB();
  CONS(1, vb);  SB(); LOADK(5, vb); SB();
  CONS(2, vc);  SB(); LOADK(6, vc); SB();
  CONS(3, vd);  SB(); LOADK(7, vd); SB();
  CONS(4, va);  SB(); LOADK(8, va); SB();
  CONS(5, vb);  SB();
  CONS(6, vc);  SB();
  CONS(7, vd);  SB();
  CONS(8, va);

  #pragma unroll
  for (int o2 = 0; o2 < 8; ++o2) {
    __builtin_nontemporal_store(acc2[o2][0], &out[(size_t)(b * COUT + 2*o2    ) * NPIX + p]);
    __builtin_nontemporal_store(acc2[o2][1], &out[(size_t)(b * COUT + 2*o2 + 1) * NPIX + p]);
  }
}

// fallback if workspace too small: gather directly from fp32 x [B][C][H][W]
__global__ __launch_bounds__(256) void mconv_direct_k(const float* __restrict__ x,
                                                      const float* __restrict__ sm,
                                                      const float* __restrict__ weight,
                                                      const float* __restrict__ bias,
                                                      float* __restrict__ out) {
  __shared__ float wlds[KK * CIN * COUT];
  int tid = threadIdx.x;
  for (int i = tid; i < KK * CIN * COUT; i += 256) {
    int k = i >> 7, c = (i >> 4) & 7, o = i & 15;
    wlds[i] = weight[(o * CIN + c) * KK + k];
  }
  __syncthreads();

  int p = blockIdx.x * 256 + tid;
  if (p >= NPIX) return;

  float acc[2][COUT];
  #pragma unroll
  for (int o = 0; o < COUT; ++o) { float bv = bias[o]; acc[0][o] = bv; acc[1][o] = bv; }

  const float2* smp = (const float2*)sm;

  for (int k = 0; k < KK; ++k) {
    float2 s = smp[(size_t)p * KK + k];
    float x0f = floorf(s.x), y0f = floorf(s.y);
    float wx = s.x - x0f, wy = s.y - y0f;
    int x0 = min(max((int)x0f, 0), WW - 1);
    int y0 = min(max((int)y0f, 0), HH - 1);
    int x1 = min(x0 + 1, WW - 1), y1 = min(y0 + 1, HH - 1);
    float w00 = (1.f - wy) * (1.f - wx), w01 = (1.f - wy) * wx;
    float w10 = wy * (1.f - wx),         w11 = wy * wx;

    float sv[2][8];
    #pragma unroll
    for (int b = 0; b < 2; ++b) {
      #pragma unroll
      for (int c = 0; c < 8; ++c) {
        const float* xp = x + (size_t)(b * CIN + c) * NPIX;
        float v00 = xp[y0 * WW + x0], v01 = xp[y0 * WW + x1];
        float v10 = xp[y1 * WW + x0], v11 = xp[y1 * WW + x1];
        sv[b][c] = w00 * v00 + w01 * v01 + w10 * v10 + w11 * v11;
      }
    }

    const float4* w4 = (const float4*)&wlds[k * (CIN * COUT)];
    #pragma unroll
    for (int c = 0; c < 8; ++c) {
      float s0 = sv[0][c], s1 = sv[1][c];
      #pragma unroll
      for (int og = 0; og < 4; ++og) {
        float4 wv = w4[c * 4 + og];
        acc[0][og*4+0] += s0 * wv.x; acc[1][og*4+0] += s1 * wv.x;
        acc[0][og*4+1] += s0 * wv.y; acc[1][og*4+1] += s1 * wv.y;
        acc[0][og*4+2] += s0 * wv.z; acc[1][og*4+2] += s1 * wv.z;
        acc[0][og*4+3] += s0 * wv.w; acc[1][og*4+3] += s1 * wv.w;
      }
    }
  }

  #pragma unroll
  for (int b = 0; b < 2; ++b)
    #pragma unroll
    for (int o = 0; o < COUT; ++o)
      out[(size_t)(b * COUT + o) * NPIX + p] = acc[b][o];
}

extern "C" void kernel_launch(void* const* d_in, const int* in_sizes, int n_in,
                              void* d_out, int out_size, void* d_ws, size_t ws_size,
                              hipStream_t stream) {
  const float* x      = (const float*)d_in[0];
  const float* sm     = (const float*)d_in[1];
  const float* weight = (const float*)d_in[2];
  const float* bias   = (const float*)d_in[3];
  float* out = (float*)d_out;

  const size_t oneCopy = (size_t)COPY4 * sizeof(uint4);   // 16 MB
  uint4* xt4 = (uint4*)d_ws;
  if (ws_size >= 4 * oneCopy) {
    hipLaunchKernelGGL(xpose4_k, dim3((HH / 32) * (WW / 32)), dim3(256), 0,
                       stream, x, xt4);
    hipLaunchKernelGGL(mconv9_k, dim3(NPIX / 128), dim3(256), 0, stream,
                       xt4, sm, weight, bias, out);
  } else {
    hipLaunchKernelGGL(mconv_direct_k, dim3((NPIX + 255) / 256), dim3(256), 0, stream,
                       x, sm, weight, bias, out);
  }
}